// Round 1
// baseline (1208.415 us; speedup 1.0000x reference)
//
#include <hip/hip_runtime.h>
#include <hip/hip_bf16.h>
#include <math.h>

#define LORA_SCALE 8.0f

// ---------------- K1/K5: lora down-projection  out[M,4] = X[M,K] @ A[K,4] ----------------
__global__ __launch_bounds__(64) void lora_down_kernel(
    const float* __restrict__ X, const float* __restrict__ A,
    float* __restrict__ out, int K)
{
    const int row = blockIdx.x;
    const int lane = threadIdx.x;
    const float* xr = X + (size_t)row * K;
    float a0 = 0.f, a1 = 0.f, a2 = 0.f, a3 = 0.f;
    for (int c = lane; c < K; c += 64) {
        float xv = xr[c];
        float4 av = *(const float4*)&A[c * 4];
        a0 = fmaf(xv, av.x, a0);
        a1 = fmaf(xv, av.y, a1);
        a2 = fmaf(xv, av.z, a2);
        a3 = fmaf(xv, av.w, a3);
    }
#pragma unroll
    for (int off = 32; off > 0; off >>= 1) {
        a0 += __shfl_down(a0, off);
        a1 += __shfl_down(a1, off);
        a2 += __shfl_down(a2, off);
        a3 += __shfl_down(a3, off);
    }
    if (lane == 0) {
        float4 r; r.x = a0; r.y = a1; r.z = a2; r.w = a3;
        *(float4*)&out[(size_t)row * 4] = r;
    }
}

// ---------------- K2/K4: tiled fp32 GEMM, 64x64 tile, optional LoRA/bias epilogue --------
// C[M,N] = A[M,K] @ B[K,N]  (+ LORA_SCALE * XA[M,4] @ LB[4,N]) (+ bias[N])
template<bool LORA, bool BIAS>
__global__ __launch_bounds__(256) void gemm64_kernel(
    const float* __restrict__ A, const float* __restrict__ B,
    float* __restrict__ C, int M, int N, int K,
    const float* __restrict__ XA, const float* __restrict__ LB,
    const float* __restrict__ bias)
{
    __shared__ float As[16][64];   // [k][m]
    __shared__ float Bs[16][64];   // [k][n]
    const int bm = blockIdx.y * 64;
    const int bn = blockIdx.x * 64;
    const int tid = threadIdx.x;
    const int tx = tid & 15;
    const int ty = tid >> 4;
    const int ar = tid >> 2;            // A row within tile 0..63
    const int ak = (tid & 3) << 2;      // A k within tile 0,4,8,12
    const int bk = tid >> 4;            // B k within tile 0..15
    const int bn0 = (tid & 15) << 2;    // B n within tile 0..60

    float acc[4][4] = {};

    for (int k0 = 0; k0 < K; k0 += 16) {
        float4 av = *(const float4*)&A[(size_t)(bm + ar) * K + k0 + ak];
        float4 bv = *(const float4*)&B[(size_t)(k0 + bk) * N + bn + bn0];
        As[ak + 0][ar] = av.x;
        As[ak + 1][ar] = av.y;
        As[ak + 2][ar] = av.z;
        As[ak + 3][ar] = av.w;
        *(float4*)&Bs[bk][bn0] = bv;
        __syncthreads();
#pragma unroll
        for (int k = 0; k < 16; ++k) {
            float4 a4 = *(const float4*)&As[k][ty * 4];
            float4 b4 = *(const float4*)&Bs[k][tx * 4];
            float avr[4] = {a4.x, a4.y, a4.z, a4.w};
            float bvr[4] = {b4.x, b4.y, b4.z, b4.w};
#pragma unroll
            for (int i = 0; i < 4; ++i)
#pragma unroll
                for (int j = 0; j < 4; ++j)
                    acc[i][j] = fmaf(avr[i], bvr[j], acc[i][j]);
        }
        __syncthreads();
    }

    const int col = bn + tx * 4;
    float4 lb0, lb1, lb2, lb3;
    if (LORA) {
        lb0 = *(const float4*)&LB[0 * N + col];
        lb1 = *(const float4*)&LB[1 * N + col];
        lb2 = *(const float4*)&LB[2 * N + col];
        lb3 = *(const float4*)&LB[3 * N + col];
    }
    float4 bv4 = {0.f, 0.f, 0.f, 0.f};
    if (BIAS) bv4 = *(const float4*)&bias[col];

#pragma unroll
    for (int i = 0; i < 4; ++i) {
        const int row = bm + ty * 4 + i;
        float4 r;
        r.x = acc[i][0]; r.y = acc[i][1]; r.z = acc[i][2]; r.w = acc[i][3];
        if (LORA) {
            float4 xa4 = *(const float4*)&XA[(size_t)row * 4];
            r.x += LORA_SCALE * (xa4.x * lb0.x + xa4.y * lb1.x + xa4.z * lb2.x + xa4.w * lb3.x);
            r.y += LORA_SCALE * (xa4.x * lb0.y + xa4.y * lb1.y + xa4.z * lb2.y + xa4.w * lb3.y);
            r.z += LORA_SCALE * (xa4.x * lb0.z + xa4.y * lb1.z + xa4.z * lb2.z + xa4.w * lb3.z);
            r.w += LORA_SCALE * (xa4.x * lb0.w + xa4.y * lb1.w + xa4.z * lb2.w + xa4.w * lb3.w);
        }
        if (BIAS) { r.x += bv4.x; r.y += bv4.y; r.z += bv4.z; r.w += bv4.w; }
        *(float4*)&C[(size_t)row * N + col] = r;
    }
}

// ---------------- K3: flash attention, fp32, one q-row per thread ----------------
// qkv layout: [B*N, 2304], col = three*768 + h*64 + dd
__global__ __launch_bounds__(256) void flash_kernel(
    const float* __restrict__ qkv, float* __restrict__ out)
{
    const int bh = blockIdx.y;           // 0..95
    const int b = bh / 12;
    const int h = bh - b * 12;
    const int qr = blockIdx.x * 256 + threadIdx.x;   // q row within sequence
    const float* base = qkv + (size_t)b * 1024 * 2304;
    const float* qrow = base + (size_t)qr * 2304 + h * 64;

    float q[64];
#pragma unroll
    for (int i = 0; i < 16; ++i) {
        float4 t = *(const float4*)&qrow[i * 4];
        q[i * 4 + 0] = t.x * 0.125f;   // pre-apply scale = d^-0.5 = 0.125
        q[i * 4 + 1] = t.y * 0.125f;
        q[i * 4 + 2] = t.z * 0.125f;
        q[i * 4 + 3] = t.w * 0.125f;
    }
    float o[64];
#pragma unroll
    for (int i = 0; i < 64; ++i) o[i] = 0.f;
    float mmax = -1e30f, l = 0.f;

    __shared__ float kt[32][64];
    __shared__ float vt[32][64];
    const int sr = threadIdx.x >> 3;         // 0..31
    const int sc = (threadIdx.x & 7) * 8;    // 0..56

    for (int m0 = 0; m0 < 1024; m0 += 32) {
        __syncthreads();
        const float* kr = base + (size_t)(m0 + sr) * 2304 + 768 + h * 64 + sc;
        const float* vr = kr + 768;
        float4 k0v = *(const float4*)&kr[0];
        float4 k1v = *(const float4*)&kr[4];
        float4 v0v = *(const float4*)&vr[0];
        float4 v1v = *(const float4*)&vr[4];
        *(float4*)&kt[sr][sc]     = k0v;
        *(float4*)&kt[sr][sc + 4] = k1v;
        *(float4*)&vt[sr][sc]     = v0v;
        *(float4*)&vt[sr][sc + 4] = v1v;
        __syncthreads();

        for (int m = 0; m < 32; ++m) {
            float s = 0.f;
#pragma unroll
            for (int i = 0; i < 16; ++i) {
                float4 kv = *(const float4*)&kt[m][i * 4];
                s = fmaf(q[i * 4 + 0], kv.x, s);
                s = fmaf(q[i * 4 + 1], kv.y, s);
                s = fmaf(q[i * 4 + 2], kv.z, s);
                s = fmaf(q[i * 4 + 3], kv.w, s);
            }
            if (s > mmax) {                 // rare: running-max update + rescale
                float corr = __expf(mmax - s);
                l *= corr;
#pragma unroll
                for (int i = 0; i < 64; ++i) o[i] *= corr;
                mmax = s;
            }
            float p = __expf(s - mmax);
            l += p;
#pragma unroll
            for (int i = 0; i < 16; ++i) {
                float4 vv = *(const float4*)&vt[m][i * 4];
                o[i * 4 + 0] = fmaf(p, vv.x, o[i * 4 + 0]);
                o[i * 4 + 1] = fmaf(p, vv.y, o[i * 4 + 1]);
                o[i * 4 + 2] = fmaf(p, vv.z, o[i * 4 + 2]);
                o[i * 4 + 3] = fmaf(p, vv.w, o[i * 4 + 3]);
            }
        }
    }
    const float inv = 1.f / l;
    float* orow = out + (size_t)(b * 1024 + qr) * 768 + h * 64;
#pragma unroll
    for (int i = 0; i < 16; ++i) {
        float4 r;
        r.x = o[i * 4 + 0] * inv;
        r.y = o[i * 4 + 1] * inv;
        r.z = o[i * 4 + 2] * inv;
        r.w = o[i * 4 + 3] * inv;
        *(float4*)&orow[i * 4] = r;
    }
}

// ---------------- K6: out += LORA_SCALE * pa[M,4] @ Bp[4,768] (in place) ----------------
__global__ __launch_bounds__(256) void lora_up_add_kernel(
    float* __restrict__ out, const float* __restrict__ pa,
    const float* __restrict__ Bp)
{
    const int idx = blockIdx.x * 256 + threadIdx.x;   // one float4 per thread
    const int row = idx / 192;
    const int col = (idx - row * 192) * 4;
    float4 p4 = *(const float4*)&pa[(size_t)row * 4];
    float4 b0 = *(const float4*)&Bp[0 * 768 + col];
    float4 b1 = *(const float4*)&Bp[1 * 768 + col];
    float4 b2 = *(const float4*)&Bp[2 * 768 + col];
    float4 b3 = *(const float4*)&Bp[3 * 768 + col];
    float* op = &out[(size_t)row * 768 + col];
    float4 o = *(float4*)op;
    o.x += LORA_SCALE * (p4.x * b0.x + p4.y * b1.x + p4.z * b2.x + p4.w * b3.x);
    o.y += LORA_SCALE * (p4.x * b0.y + p4.y * b1.y + p4.z * b2.y + p4.w * b3.y);
    o.z += LORA_SCALE * (p4.x * b0.z + p4.y * b1.z + p4.z * b2.z + p4.w * b3.z);
    o.w += LORA_SCALE * (p4.x * b0.w + p4.y * b1.w + p4.z * b2.w + p4.w * b3.w);
    *(float4*)op = o;
}

extern "C" void kernel_launch(void* const* d_in, const int* in_sizes, int n_in,
                              void* d_out, int out_size, void* d_ws, size_t ws_size,
                              hipStream_t stream)
{
    const float* x      = (const float*)d_in[0];
    const float* W_qkv  = (const float*)d_in[1];
    const float* W_proj = (const float*)d_in[2];
    const float* b_proj = (const float*)d_in[3];
    const float* A_qkv  = (const float*)d_in[4];
    const float* B_qkv  = (const float*)d_in[5];
    const float* A_proj = (const float*)d_in[6];
    const float* B_proj = (const float*)d_in[7];
    float* out = (float*)d_out;

    char* ws = (char*)d_ws;
    float* xa  = (float*)(ws);                                  //  8192*4 f32
    float* pa  = (float*)(ws + 131072);                         //  8192*4 f32
    float* qkv = (float*)(ws + 262144);                         //  8192*2304 f32
    float* ao  = (float*)(ws + 262144 + 75497472ull);           //  8192*768 f32

    const int M = 8192;   // B*N = 8*1024

    // 1) xa = x @ A_qkv
    lora_down_kernel<<<dim3(M), dim3(64), 0, stream>>>(x, A_qkv, xa, 768);
    // 2) qkv = x @ W_qkv + 8 * xa @ B_qkv
    gemm64_kernel<true, false><<<dim3(2304 / 64, M / 64), dim3(256), 0, stream>>>(
        x, W_qkv, qkv, M, 2304, 768, xa, B_qkv, nullptr);
    // 3) flash attention -> ao [8192, 768]
    flash_kernel<<<dim3(4, 96), dim3(256), 0, stream>>>(qkv, ao);
    // 4) out = ao @ W_proj + b_proj   (staged in d_out)
    gemm64_kernel<false, true><<<dim3(768 / 64, M / 64), dim3(256), 0, stream>>>(
        ao, W_proj, out, M, 768, 768, nullptr, nullptr, b_proj);
    // 5) pa = out @ A_proj
    lora_down_kernel<<<dim3(M), dim3(64), 0, stream>>>(out, A_proj, pa, 768);
    // 6) out += 8 * pa @ B_proj
    lora_up_add_kernel<<<dim3(6144), dim3(256), 0, stream>>>(out, pa, B_proj);
}

// Round 2
// 1114.746 us; speedup vs baseline: 1.0840x; 1.0840x over previous
//
#include <hip/hip_runtime.h>
#include <hip/hip_bf16.h>
#include <math.h>

#define LORA_SCALE 8.0f

// ---------------- K1/K5: lora down-projection  out[M,4] = X[M,K] @ A[K,4] ----------------
__global__ __launch_bounds__(64) void lora_down_kernel(
    const float* __restrict__ X, const float* __restrict__ A,
    float* __restrict__ out, int K)
{
    const int row = blockIdx.x;
    const int lane = threadIdx.x;
    const float* xr = X + (size_t)row * K;
    float a0 = 0.f, a1 = 0.f, a2 = 0.f, a3 = 0.f;
    for (int c = lane; c < K; c += 64) {
        float xv = xr[c];
        float4 av = *(const float4*)&A[c * 4];
        a0 = fmaf(xv, av.x, a0);
        a1 = fmaf(xv, av.y, a1);
        a2 = fmaf(xv, av.z, a2);
        a3 = fmaf(xv, av.w, a3);
    }
#pragma unroll
    for (int off = 32; off > 0; off >>= 1) {
        a0 += __shfl_down(a0, off);
        a1 += __shfl_down(a1, off);
        a2 += __shfl_down(a2, off);
        a3 += __shfl_down(a3, off);
    }
    if (lane == 0) {
        float4 r; r.x = a0; r.y = a1; r.z = a2; r.w = a3;
        *(float4*)&out[(size_t)row * 4] = r;
    }
}

// ---------------- K2/K4: tiled fp32 GEMM, 64x64 tile, optional LoRA/bias epilogue --------
// C[M,N] = A[M,K] @ B[K,N]  (+ LORA_SCALE * XA[M,4] @ LB[4,N]) (+ bias[N])
template<bool LORA, bool BIAS>
__global__ __launch_bounds__(256) void gemm64_kernel(
    const float* __restrict__ A, const float* __restrict__ B,
    float* __restrict__ C, int M, int N, int K,
    const float* __restrict__ XA, const float* __restrict__ LB,
    const float* __restrict__ bias)
{
    __shared__ float As[16][64];   // [k][m]
    __shared__ float Bs[16][64];   // [k][n]
    const int bm = blockIdx.y * 64;
    const int bn = blockIdx.x * 64;
    const int tid = threadIdx.x;
    const int tx = tid & 15;
    const int ty = tid >> 4;
    const int ar = tid >> 2;            // A row within tile 0..63
    const int ak = (tid & 3) << 2;      // A k within tile 0,4,8,12
    const int bk = tid >> 4;            // B k within tile 0..15
    const int bn0 = (tid & 15) << 2;    // B n within tile 0..60

    float acc[4][4] = {};

    for (int k0 = 0; k0 < K; k0 += 16) {
        float4 av = *(const float4*)&A[(size_t)(bm + ar) * K + k0 + ak];
        float4 bv = *(const float4*)&B[(size_t)(k0 + bk) * N + bn + bn0];
        As[ak + 0][ar] = av.x;
        As[ak + 1][ar] = av.y;
        As[ak + 2][ar] = av.z;
        As[ak + 3][ar] = av.w;
        *(float4*)&Bs[bk][bn0] = bv;
        __syncthreads();
#pragma unroll
        for (int k = 0; k < 16; ++k) {
            float4 a4 = *(const float4*)&As[k][ty * 4];
            float4 b4 = *(const float4*)&Bs[k][tx * 4];
            float avr[4] = {a4.x, a4.y, a4.z, a4.w};
            float bvr[4] = {b4.x, b4.y, b4.z, b4.w};
#pragma unroll
            for (int i = 0; i < 4; ++i)
#pragma unroll
                for (int j = 0; j < 4; ++j)
                    acc[i][j] = fmaf(avr[i], bvr[j], acc[i][j]);
        }
        __syncthreads();
    }

    const int col = bn + tx * 4;
    float4 lb0, lb1, lb2, lb3;
    if (LORA) {
        lb0 = *(const float4*)&LB[0 * N + col];
        lb1 = *(const float4*)&LB[1 * N + col];
        lb2 = *(const float4*)&LB[2 * N + col];
        lb3 = *(const float4*)&LB[3 * N + col];
    }
    float4 bv4 = {0.f, 0.f, 0.f, 0.f};
    if (BIAS) bv4 = *(const float4*)&bias[col];

#pragma unroll
    for (int i = 0; i < 4; ++i) {
        const int row = bm + ty * 4 + i;
        float4 r;
        r.x = acc[i][0]; r.y = acc[i][1]; r.z = acc[i][2]; r.w = acc[i][3];
        if (LORA) {
            float4 xa4 = *(const float4*)&XA[(size_t)row * 4];
            r.x += LORA_SCALE * (xa4.x * lb0.x + xa4.y * lb1.x + xa4.z * lb2.x + xa4.w * lb3.x);
            r.y += LORA_SCALE * (xa4.x * lb0.y + xa4.y * lb1.y + xa4.z * lb2.y + xa4.w * lb3.y);
            r.z += LORA_SCALE * (xa4.x * lb0.z + xa4.y * lb1.z + xa4.z * lb2.z + xa4.w * lb3.z);
            r.w += LORA_SCALE * (xa4.x * lb0.w + xa4.y * lb1.w + xa4.z * lb2.w + xa4.w * lb3.w);
        }
        if (BIAS) { r.x += bv4.x; r.y += bv4.y; r.z += bv4.z; r.w += bv4.w; }
        *(float4*)&C[(size_t)row * N + col] = r;
    }
}

// ---------------- K3: flash attention v2 — 2 threads per q-row (32 dims each) ----------
// Fixes: register spill (q[64]+o[64] > 80 VGPR), occupancy cap (1.5 waves/SIMD),
// LDS bank conflicts (pad 64->68). Adds next-tile register prefetch (issue-early,
// write-late) so global latency hides under the 32-key inner loop.
// qkv layout: [B*N, 2304], col = three*768 + h*64 + dd
__global__ __launch_bounds__(256) void flash2_kernel(
    const float* __restrict__ qkv, float* __restrict__ out)
{
    const int bh = blockIdx.y;           // 0..95
    const int b = bh / 12;
    const int h = bh - b * 12;
    const int tid = threadIdx.x;
    const int qr = blockIdx.x * 128 + (tid >> 1);   // q row within sequence
    const int hf = tid & 1;                          // which 32-dim half
    const float* base = qkv + (size_t)b * 1024 * 2304;
    const float* qrow = base + (size_t)qr * 2304 + h * 64 + hf * 32;

    float q[32];
#pragma unroll
    for (int i = 0; i < 8; ++i) {
        float4 t = *(const float4*)&qrow[i * 4];
        q[i * 4 + 0] = t.x * 0.125f;   // pre-apply scale = d^-0.5
        q[i * 4 + 1] = t.y * 0.125f;
        q[i * 4 + 2] = t.z * 0.125f;
        q[i * 4 + 3] = t.w * 0.125f;
    }
    float o[32];
#pragma unroll
    for (int i = 0; i < 32; ++i) o[i] = 0.f;
    float mmax = -1e30f, l = 0.f;

    __shared__ float kt[32][68];   // +4 pad: staging writes spread across banks
    __shared__ float vt[32][68];
    const int sr = tid >> 3;         // 0..31
    const int sc = (tid & 7) * 8;    // 0..56

    // prefetch tile 0 into registers
    const float* kr = base + (size_t)sr * 2304 + 768 + h * 64 + sc;
    const float* vr = kr + 768;
    float4 pk0 = *(const float4*)&kr[0];
    float4 pk1 = *(const float4*)&kr[4];
    float4 pv0 = *(const float4*)&vr[0];
    float4 pv1 = *(const float4*)&vr[4];

    for (int m0 = 0; m0 < 1024; m0 += 32) {
        __syncthreads();   // previous tile's readers done
        *(float4*)&kt[sr][sc]     = pk0;
        *(float4*)&kt[sr][sc + 4] = pk1;
        *(float4*)&vt[sr][sc]     = pv0;
        *(float4*)&vt[sr][sc + 4] = pv1;
        if (m0 + 32 < 1024) {      // issue next-tile loads; latency hides under inner loop
            const float* krn = kr + (size_t)(m0 + 32) * 2304;
            const float* vrn = krn + 768;
            pk0 = *(const float4*)&krn[0];
            pk1 = *(const float4*)&krn[4];
            pv0 = *(const float4*)&vrn[0];
            pv1 = *(const float4*)&vrn[4];
        }
        __syncthreads();

        for (int m = 0; m < 32; ++m) {
            const float* krow = &kt[m][hf * 32];
            float s0 = 0.f, s1 = 0.f, s2 = 0.f, s3 = 0.f;
#pragma unroll
            for (int i = 0; i < 8; i += 4) {
                float4 k0v = *(const float4*)&krow[(i + 0) * 4];
                float4 k1v = *(const float4*)&krow[(i + 1) * 4];
                float4 k2v = *(const float4*)&krow[(i + 2) * 4];
                float4 k3v = *(const float4*)&krow[(i + 3) * 4];
                s0 = fmaf(q[i * 4 + 0], k0v.x, s0);
                s0 = fmaf(q[i * 4 + 1], k0v.y, s0);
                s0 = fmaf(q[i * 4 + 2], k0v.z, s0);
                s0 = fmaf(q[i * 4 + 3], k0v.w, s0);
                s1 = fmaf(q[i * 4 + 4], k1v.x, s1);
                s1 = fmaf(q[i * 4 + 5], k1v.y, s1);
                s1 = fmaf(q[i * 4 + 6], k1v.z, s1);
                s1 = fmaf(q[i * 4 + 7], k1v.w, s1);
                s2 = fmaf(q[i * 4 + 8], k2v.x, s2);
                s2 = fmaf(q[i * 4 + 9], k2v.y, s2);
                s2 = fmaf(q[i * 4 + 10], k2v.z, s2);
                s2 = fmaf(q[i * 4 + 11], k2v.w, s2);
                s3 = fmaf(q[i * 4 + 12], k3v.x, s3);
                s3 = fmaf(q[i * 4 + 13], k3v.y, s3);
                s3 = fmaf(q[i * 4 + 14], k3v.z, s3);
                s3 = fmaf(q[i * 4 + 15], k3v.w, s3);
            }
            float sh = (s0 + s1) + (s2 + s3);
            float s = sh + __shfl_xor(sh, 1);   // combine the two 32-dim halves

            if (s > mmax) {                 // rare: running-max update + rescale
                float corr = __expf(mmax - s);
                l *= corr;
#pragma unroll
                for (int i = 0; i < 32; ++i) o[i] *= corr;
                mmax = s;
            }
            float p = __expf(s - mmax);
            l += p;
            const float* vrow = &vt[m][hf * 32];
#pragma unroll
            for (int i = 0; i < 8; ++i) {
                float4 vv = *(const float4*)&vrow[i * 4];
                o[i * 4 + 0] = fmaf(p, vv.x, o[i * 4 + 0]);
                o[i * 4 + 1] = fmaf(p, vv.y, o[i * 4 + 1]);
                o[i * 4 + 2] = fmaf(p, vv.z, o[i * 4 + 2]);
                o[i * 4 + 3] = fmaf(p, vv.w, o[i * 4 + 3]);
            }
        }
    }
    const float inv = 1.f / l;
    float* orow = out + (size_t)(b * 1024 + qr) * 768 + h * 64 + hf * 32;
#pragma unroll
    for (int i = 0; i < 8; ++i) {
        float4 r;
        r.x = o[i * 4 + 0] * inv;
        r.y = o[i * 4 + 1] * inv;
        r.z = o[i * 4 + 2] * inv;
        r.w = o[i * 4 + 3] * inv;
        *(float4*)&orow[i * 4] = r;
    }
}

// ---------------- K6: out += LORA_SCALE * pa[M,4] @ Bp[4,768] (in place) ----------------
__global__ __launch_bounds__(256) void lora_up_add_kernel(
    float* __restrict__ out, const float* __restrict__ pa,
    const float* __restrict__ Bp)
{
    const int idx = blockIdx.x * 256 + threadIdx.x;   // one float4 per thread
    const int row = idx / 192;
    const int col = (idx - row * 192) * 4;
    float4 p4 = *(const float4*)&pa[(size_t)row * 4];
    float4 b0 = *(const float4*)&Bp[0 * 768 + col];
    float4 b1 = *(const float4*)&Bp[1 * 768 + col];
    float4 b2 = *(const float4*)&Bp[2 * 768 + col];
    float4 b3 = *(const float4*)&Bp[3 * 768 + col];
    float* op = &out[(size_t)row * 768 + col];
    float4 o = *(float4*)op;
    o.x += LORA_SCALE * (p4.x * b0.x + p4.y * b1.x + p4.z * b2.x + p4.w * b3.x);
    o.y += LORA_SCALE * (p4.x * b0.y + p4.y * b1.y + p4.z * b2.y + p4.w * b3.y);
    o.z += LORA_SCALE * (p4.x * b0.z + p4.y * b1.z + p4.z * b2.z + p4.w * b3.z);
    o.w += LORA_SCALE * (p4.x * b0.w + p4.y * b1.w + p4.z * b2.w + p4.w * b3.w);
    *(float4*)op = o;
}

extern "C" void kernel_launch(void* const* d_in, const int* in_sizes, int n_in,
                              void* d_out, int out_size, void* d_ws, size_t ws_size,
                              hipStream_t stream)
{
    const float* x      = (const float*)d_in[0];
    const float* W_qkv  = (const float*)d_in[1];
    const float* W_proj = (const float*)d_in[2];
    const float* b_proj = (const float*)d_in[3];
    const float* A_qkv  = (const float*)d_in[4];
    const float* B_qkv  = (const float*)d_in[5];
    const float* A_proj = (const float*)d_in[6];
    const float* B_proj = (const float*)d_in[7];
    float* out = (float*)d_out;

    char* ws = (char*)d_ws;
    float* xa  = (float*)(ws);                                  //  8192*4 f32
    float* pa  = (float*)(ws + 131072);                         //  8192*4 f32
    float* qkv = (float*)(ws + 262144);                         //  8192*2304 f32
    float* ao  = (float*)(ws + 262144 + 75497472ull);           //  8192*768 f32

    const int M = 8192;   // B*N = 8*1024

    // 1) xa = x @ A_qkv
    lora_down_kernel<<<dim3(M), dim3(64), 0, stream>>>(x, A_qkv, xa, 768);
    // 2) qkv = x @ W_qkv + 8 * xa @ B_qkv
    gemm64_kernel<true, false><<<dim3(2304 / 64, M / 64), dim3(256), 0, stream>>>(
        x, W_qkv, qkv, M, 2304, 768, xa, B_qkv, nullptr);
    // 3) flash attention -> ao [8192, 768]  (2 threads per q-row, 128 rows/block)
    flash2_kernel<<<dim3(8, 96), dim3(256), 0, stream>>>(qkv, ao);
    // 4) out = ao @ W_proj + b_proj   (staged in d_out)
    gemm64_kernel<false, true><<<dim3(768 / 64, M / 64), dim3(256), 0, stream>>>(
        ao, W_proj, out, M, 768, 768, nullptr, nullptr, b_proj);
    // 5) pa = out @ A_proj
    lora_down_kernel<<<dim3(M), dim3(64), 0, stream>>>(out, A_proj, pa, 768);
    // 6) out += 8 * pa @ B_proj
    lora_up_add_kernel<<<dim3(6144), dim3(256), 0, stream>>>(out, pa, B_proj);
}

// Round 3
// 674.719 us; speedup vs baseline: 1.7910x; 1.6522x over previous
//
#include <hip/hip_runtime.h>
#include <hip/hip_bf16.h>
#include <math.h>

#define LORA_SCALE 8.0f

typedef __attribute__((ext_vector_type(8))) short bf16x8;
typedef __attribute__((ext_vector_type(4))) float f32x4;

__device__ __forceinline__ unsigned short f2bf(float f) {
    unsigned int u = __float_as_uint(f);
    u += 0x7FFFu + ((u >> 16) & 1u);      // RNE to bf16
    return (unsigned short)(u >> 16);
}
__device__ __forceinline__ unsigned int pack2(float lo, float hi) {
    return (unsigned int)f2bf(lo) | ((unsigned int)f2bf(hi) << 16);
}

union Frag { bf16x8 v; unsigned int u[4]; };

// ---------------- K1/K5: lora down-projection  out[M,4] = X[M,K] @ A[K,4] ----------------
__global__ __launch_bounds__(64) void lora_down_kernel(
    const float* __restrict__ X, const float* __restrict__ A,
    float* __restrict__ out, int K)
{
    const int row = blockIdx.x;
    const int lane = threadIdx.x;
    const float* xr = X + (size_t)row * K;
    float a0 = 0.f, a1 = 0.f, a2 = 0.f, a3 = 0.f;
    for (int c = lane; c < K; c += 64) {
        float xv = xr[c];
        float4 av = *(const float4*)&A[c * 4];
        a0 = fmaf(xv, av.x, a0);
        a1 = fmaf(xv, av.y, a1);
        a2 = fmaf(xv, av.z, a2);
        a3 = fmaf(xv, av.w, a3);
    }
#pragma unroll
    for (int off = 32; off > 0; off >>= 1) {
        a0 += __shfl_down(a0, off);
        a1 += __shfl_down(a1, off);
        a2 += __shfl_down(a2, off);
        a3 += __shfl_down(a3, off);
    }
    if (lane == 0) {
        float4 r; r.x = a0; r.y = a1; r.z = a2; r.w = a3;
        *(float4*)&out[(size_t)row * 4] = r;
    }
}

// ---------------- K2/K4: tiled fp32 GEMM, 64x64 tile, optional LoRA/bias epilogue --------
template<bool LORA, bool BIAS>
__global__ __launch_bounds__(256) void gemm64_kernel(
    const float* __restrict__ A, const float* __restrict__ B,
    float* __restrict__ C, int M, int N, int K,
    const float* __restrict__ XA, const float* __restrict__ LB,
    const float* __restrict__ bias)
{
    __shared__ float As[16][64];   // [k][m]
    __shared__ float Bs[16][64];   // [k][n]
    const int bm = blockIdx.y * 64;
    const int bn = blockIdx.x * 64;
    const int tid = threadIdx.x;
    const int tx = tid & 15;
    const int ty = tid >> 4;
    const int ar = tid >> 2;
    const int ak = (tid & 3) << 2;
    const int bk = tid >> 4;
    const int bn0 = (tid & 15) << 2;

    float acc[4][4] = {};

    for (int k0 = 0; k0 < K; k0 += 16) {
        float4 av = *(const float4*)&A[(size_t)(bm + ar) * K + k0 + ak];
        float4 bv = *(const float4*)&B[(size_t)(k0 + bk) * N + bn + bn0];
        As[ak + 0][ar] = av.x;
        As[ak + 1][ar] = av.y;
        As[ak + 2][ar] = av.z;
        As[ak + 3][ar] = av.w;
        *(float4*)&Bs[bk][bn0] = bv;
        __syncthreads();
#pragma unroll
        for (int k = 0; k < 16; ++k) {
            float4 a4 = *(const float4*)&As[k][ty * 4];
            float4 b4 = *(const float4*)&Bs[k][tx * 4];
            float avr[4] = {a4.x, a4.y, a4.z, a4.w};
            float bvr[4] = {b4.x, b4.y, b4.z, b4.w};
#pragma unroll
            for (int i = 0; i < 4; ++i)
#pragma unroll
                for (int j = 0; j < 4; ++j)
                    acc[i][j] = fmaf(avr[i], bvr[j], acc[i][j]);
        }
        __syncthreads();
    }

    const int col = bn + tx * 4;
    float4 lb0, lb1, lb2, lb3;
    if (LORA) {
        lb0 = *(const float4*)&LB[0 * N + col];
        lb1 = *(const float4*)&LB[1 * N + col];
        lb2 = *(const float4*)&LB[2 * N + col];
        lb3 = *(const float4*)&LB[3 * N + col];
    }
    float4 bv4 = {0.f, 0.f, 0.f, 0.f};
    if (BIAS) bv4 = *(const float4*)&bias[col];

#pragma unroll
    for (int i = 0; i < 4; ++i) {
        const int row = bm + ty * 4 + i;
        float4 r;
        r.x = acc[i][0]; r.y = acc[i][1]; r.z = acc[i][2]; r.w = acc[i][3];
        if (LORA) {
            float4 xa4 = *(const float4*)&XA[(size_t)row * 4];
            r.x += LORA_SCALE * (xa4.x * lb0.x + xa4.y * lb1.x + xa4.z * lb2.x + xa4.w * lb3.x);
            r.y += LORA_SCALE * (xa4.x * lb0.y + xa4.y * lb1.y + xa4.z * lb2.y + xa4.w * lb3.y);
            r.z += LORA_SCALE * (xa4.x * lb0.z + xa4.y * lb1.z + xa4.z * lb2.z + xa4.w * lb3.z);
            r.w += LORA_SCALE * (xa4.x * lb0.w + xa4.y * lb1.w + xa4.z * lb2.w + xa4.w * lb3.w);
        }
        if (BIAS) { r.x += bv4.x; r.y += bv4.y; r.z += bv4.z; r.w += bv4.w; }
        *(float4*)&C[(size_t)row * N + col] = r;
    }
}

// ---------------- K3: MFMA bf16 flash attention ----------------
// Swapped-operand flash: S^T = mfma(A=K, B=Q^T) so row-softmax is 8 in-lane
// values + 2 shfl_xor. P^T -> PV B-frag via 8-shfl register exchange.
// Block = 4 waves x 32 q-rows = 128 q-rows of one (b,h).
// Grid decode f: bh = f%96, qx = f/96 -> all 8 same-(b,h) blocks share an XCD L2.
// qkv rows: [B*N][2304] fp32, Q at h*64, K at 768+h*64, V at 1536+h*64.
__global__ __launch_bounds__(256, 3) void flash_mfma_kernel(
    const float* __restrict__ qkv, float* __restrict__ out)
{
    __shared__ __align__(16) short Kl[32][72];   // [k][d] bf16, rows 144B (pad): A-frag b128 reads 2-way-free
    __shared__ __align__(16) short Vl[64][40];   // V^T [d][k] bf16, rows 80B (16B-aligned, 2-way-free)
    const int fid = blockIdx.x;
    const int bh = fid % 96;
    const int qx = fid / 96;
    const int b = bh / 12, h = bh - b * 12;
    const int tid = threadIdx.x;
    const int w = tid >> 6, lane = tid & 63;
    const int lc = lane & 15, lg = lane >> 4;
    const float* base = qkv + (size_t)b * 1024 * 2304;
    const int q0 = qx * 128 + w * 32;

    // Q B-frags: lane holds col q = lc, rows d = dc*32 + lg*8 + j.
    // Pre-scale by d^-0.5 * log2(e): softmax runs in exp2 domain.
    const float qscale = 0.125f * 1.44269504f;
    Frag qf[2][2];
#pragma unroll
    for (int qi = 0; qi < 2; ++qi)
#pragma unroll
        for (int dc = 0; dc < 2; ++dc) {
            const float* p = base + (size_t)(q0 + qi * 16 + lc) * 2304 + h * 64 + dc * 32 + lg * 8;
            float4 t0 = *(const float4*)p;
            float4 t1 = *(const float4*)(p + 4);
            qf[qi][dc].u[0] = pack2(t0.x * qscale, t0.y * qscale);
            qf[qi][dc].u[1] = pack2(t0.z * qscale, t0.w * qscale);
            qf[qi][dc].u[2] = pack2(t1.x * qscale, t1.y * qscale);
            qf[qi][dc].u[3] = pack2(t1.z * qscale, t1.w * qscale);
        }

    f32x4 o[2][4];   // O^T accum: col q = lc, row d = df*16 + lg*4 + r
#pragma unroll
    for (int qi = 0; qi < 2; ++qi)
#pragma unroll
        for (int df = 0; df < 4; ++df) o[qi][df] = (f32x4){0.f, 0.f, 0.f, 0.f};
    float mrow[2] = {-1e30f, -1e30f};
    float lrow[2] = {0.f, 0.f};

    for (int kv0 = 0; kv0 < 1024; kv0 += 32) {
        __syncthreads();   // previous tile fully consumed
        // ---- stage K [32][64] and V^T [64][32] (fp32 global -> bf16 LDS) ----
#pragma unroll
        for (int rep = 0; rep < 2; ++rep) {
            int i = tid + rep * 256;            // 0..511 float4 slots
            int kk = i >> 4, d0 = (i & 15) * 4;
            const float* gp = base + (size_t)(kv0 + kk) * 2304 + 768 + h * 64 + d0;
            float4 kv4 = *(const float4*)gp;
            float4 vv4 = *(const float4*)(gp + 768);
            *(uint2*)&Kl[kk][d0] = make_uint2(pack2(kv4.x, kv4.y), pack2(kv4.z, kv4.w));
            Vl[d0 + 0][kk] = (short)f2bf(vv4.x);
            Vl[d0 + 1][kk] = (short)f2bf(vv4.y);
            Vl[d0 + 2][kk] = (short)f2bf(vv4.z);
            Vl[d0 + 3][kk] = (short)f2bf(vv4.w);
        }
        __syncthreads();

        // A-frags: K (row k = kf*16+lc, cols d = dc*32+lg*8+j), V^T (row d = df*16+lc, cols k = lg*8+j)
        bf16x8 kA[2][2], vA[4];
#pragma unroll
        for (int kf = 0; kf < 2; ++kf)
#pragma unroll
            for (int dc = 0; dc < 2; ++dc)
                kA[kf][dc] = *(const bf16x8*)&Kl[kf * 16 + lc][dc * 32 + lg * 8];
#pragma unroll
        for (int df = 0; df < 4; ++df)
            vA[df] = *(const bf16x8*)&Vl[df * 16 + lc][lg * 8];

#pragma unroll
        for (int qi = 0; qi < 2; ++qi) {
            // S^T[k][q]: C layout col q = lc, row k = kf*16 + lg*4 + r
            f32x4 s0 = {0.f, 0.f, 0.f, 0.f}, s1 = {0.f, 0.f, 0.f, 0.f};
            s0 = __builtin_amdgcn_mfma_f32_16x16x32_bf16(kA[0][0], qf[qi][0].v, s0, 0, 0, 0);
            s0 = __builtin_amdgcn_mfma_f32_16x16x32_bf16(kA[0][1], qf[qi][1].v, s0, 0, 0, 0);
            s1 = __builtin_amdgcn_mfma_f32_16x16x32_bf16(kA[1][0], qf[qi][0].v, s1, 0, 0, 0);
            s1 = __builtin_amdgcn_mfma_f32_16x16x32_bf16(kA[1][1], qf[qi][1].v, s1, 0, 0, 0);

            // online softmax (log2 domain): reduce 8 in-lane + 2 shfl
            float pm = fmaxf(fmaxf(fmaxf(s0[0], s0[1]), fmaxf(s0[2], s0[3])),
                             fmaxf(fmaxf(s1[0], s1[1]), fmaxf(s1[2], s1[3])));
            pm = fmaxf(pm, __shfl_xor(pm, 16, 64));
            pm = fmaxf(pm, __shfl_xor(pm, 32, 64));
            float nm = fmaxf(mrow[qi], pm);
            float corr = exp2f(mrow[qi] - nm);
            mrow[qi] = nm;
            float p0[4], p1[4];
            float rs = 0.f;
#pragma unroll
            for (int r = 0; r < 4; ++r) {
                p0[r] = exp2f(s0[r] - nm); rs += p0[r];
                p1[r] = exp2f(s1[r] - nm); rs += p1[r];
            }
            rs += __shfl_xor(rs, 16, 64);
            rs += __shfl_xor(rs, 32, 64);
            lrow[qi] = lrow[qi] * corr + rs;
#pragma unroll
            for (int df = 0; df < 4; ++df) o[qi][df] *= corr;

            // P^T (lane holds k = 16f + 4*lg + r, col q = lc) -> PV B-frag
            // (lane needs col q = lc, rows k = lg*8 + j). 8-shfl exchange:
            // word c covers k = 8*lg + 2c,+1; src g' = 2*(lg&1) + (c>>1); f' = lg>>1.
            unsigned int w00 = pack2(p0[0], p0[1]);
            unsigned int w01 = pack2(p0[2], p0[3]);
            unsigned int w10 = pack2(p1[0], p1[1]);
            unsigned int w11 = pack2(p1[2], p1[3]);
            Frag pa;
            const int gsel = (lg & 1) * 2;
#pragma unroll
            for (int c = 0; c < 4; ++c) {
                int src = lc | ((gsel + (c >> 1)) << 4);
                unsigned int a0 = (unsigned int)__shfl((int)((c & 1) ? w01 : w00), src, 64);
                unsigned int a1 = (unsigned int)__shfl((int)((c & 1) ? w11 : w10), src, 64);
                pa.u[c] = (lg >> 1) ? a1 : a0;
            }
            // O^T += V^T @ P^T
#pragma unroll
            for (int df = 0; df < 4; ++df)
                o[qi][df] = __builtin_amdgcn_mfma_f32_16x16x32_bf16(vA[df], pa.v, o[qi][df], 0, 0, 0);
        }
    }

    // epilogue: normalize and store [q][d] fp32
#pragma unroll
    for (int qi = 0; qi < 2; ++qi) {
        float inv = 1.f / lrow[qi];
        float* orow = out + (size_t)(b * 1024 + q0 + qi * 16 + lc) * 768 + h * 64;
#pragma unroll
        for (int df = 0; df < 4; ++df) {
            float4 r;
            r.x = o[qi][df][0] * inv;
            r.y = o[qi][df][1] * inv;
            r.z = o[qi][df][2] * inv;
            r.w = o[qi][df][3] * inv;
            *(float4*)&orow[df * 16 + lg * 4] = r;
        }
    }
}

// ---------------- K6: out += LORA_SCALE * pa[M,4] @ Bp[4,768] (in place) ----------------
__global__ __launch_bounds__(256) void lora_up_add_kernel(
    float* __restrict__ out, const float* __restrict__ pa,
    const float* __restrict__ Bp)
{
    const int idx = blockIdx.x * 256 + threadIdx.x;
    const int row = idx / 192;
    const int col = (idx - row * 192) * 4;
    float4 p4 = *(const float4*)&pa[(size_t)row * 4];
    float4 b0 = *(const float4*)&Bp[0 * 768 + col];
    float4 b1 = *(const float4*)&Bp[1 * 768 + col];
    float4 b2 = *(const float4*)&Bp[2 * 768 + col];
    float4 b3 = *(const float4*)&Bp[3 * 768 + col];
    float* op = &out[(size_t)row * 768 + col];
    float4 o = *(float4*)op;
    o.x += LORA_SCALE * (p4.x * b0.x + p4.y * b1.x + p4.z * b2.x + p4.w * b3.x);
    o.y += LORA_SCALE * (p4.x * b0.y + p4.y * b1.y + p4.z * b2.y + p4.w * b3.y);
    o.z += LORA_SCALE * (p4.x * b0.z + p4.y * b1.z + p4.z * b2.z + p4.w * b3.z);
    o.w += LORA_SCALE * (p4.x * b0.w + p4.y * b1.w + p4.z * b2.w + p4.w * b3.w);
    *(float4*)op = o;
}

extern "C" void kernel_launch(void* const* d_in, const int* in_sizes, int n_in,
                              void* d_out, int out_size, void* d_ws, size_t ws_size,
                              hipStream_t stream)
{
    const float* x      = (const float*)d_in[0];
    const float* W_qkv  = (const float*)d_in[1];
    const float* W_proj = (const float*)d_in[2];
    const float* b_proj = (const float*)d_in[3];
    const float* A_qkv  = (const float*)d_in[4];
    const float* B_qkv  = (const float*)d_in[5];
    const float* A_proj = (const float*)d_in[6];
    const float* B_proj = (const float*)d_in[7];
    float* out = (float*)d_out;

    char* ws = (char*)d_ws;
    float* xa  = (float*)(ws);                                  //  8192*4 f32
    float* pa  = (float*)(ws + 131072);                         //  8192*4 f32
    float* qkv = (float*)(ws + 262144);                         //  8192*2304 f32
    float* ao  = (float*)(ws + 262144 + 75497472ull);           //  8192*768 f32

    const int M = 8192;   // B*N

    // 1) xa = x @ A_qkv
    lora_down_kernel<<<dim3(M), dim3(64), 0, stream>>>(x, A_qkv, xa, 768);
    // 2) qkv = x @ W_qkv + 8 * xa @ B_qkv
    gemm64_kernel<true, false><<<dim3(2304 / 64, M / 64), dim3(256), 0, stream>>>(
        x, W_qkv, qkv, M, 2304, 768, xa, B_qkv, nullptr);
    // 3) MFMA flash attention -> ao [8192, 768]
    flash_mfma_kernel<<<dim3(768), dim3(256), 0, stream>>>(qkv, ao);
    // 4) out = ao @ W_proj + b_proj
    gemm64_kernel<false, true><<<dim3(768 / 64, M / 64), dim3(256), 0, stream>>>(
        ao, W_proj, out, M, 768, 768, nullptr, nullptr, b_proj);
    // 5) pa = out @ A_proj
    lora_down_kernel<<<dim3(M), dim3(64), 0, stream>>>(out, A_proj, pa, 768);
    // 6) out += 8 * pa @ B_proj
    lora_up_add_kernel<<<dim3(6144), dim3(256), 0, stream>>>(out, pa, B_proj);
}

// Round 4
// 341.534 us; speedup vs baseline: 3.5382x; 1.9756x over previous
//
#include <hip/hip_runtime.h>
#include <hip/hip_bf16.h>
#include <math.h>

#define LORA_SCALE 8.0f

typedef __attribute__((ext_vector_type(8))) short bf16x8;
typedef __attribute__((ext_vector_type(4))) float f32x4;
typedef unsigned short u16;
typedef unsigned int u32;

__device__ __forceinline__ u16 f2bf(float f) {
    u32 u = __float_as_uint(f);
    u += 0x7FFFu + ((u >> 16) & 1u);      // RNE to bf16
    return (u16)(u >> 16);
}
__device__ __forceinline__ float bf2f(u16 s) {
    return __uint_as_float(((u32)s) << 16);
}
// split a,b into hi/lo bf16 pairs packed as words
__device__ __forceinline__ void split2(float a, float b, u32& hw, u32& lw) {
    u16 ha = f2bf(a), hb = f2bf(b);
    float ra = a - bf2f(ha), rb = b - bf2f(hb);
    hw = (u32)ha | ((u32)hb << 16);
    lw = (u32)f2bf(ra) | ((u32)f2bf(rb) << 16);
}

__device__ __forceinline__ void g2lds16(const void* g, void* l) {
    __builtin_amdgcn_global_load_lds(
        (const __attribute__((address_space(1))) void*)g,
        (__attribute__((address_space(3))) void*)l, 16, 0, 0);
}

union Frag { bf16x8 v; u32 u[4]; };

// ---------------- pre-pass: split f32 -> bf16 hi/lo (8 elems/thread) ----------------
__global__ __launch_bounds__(256) void split_kernel(
    const float* __restrict__ in, u16* __restrict__ hi, u16* __restrict__ lo, int n8)
{
    int i = blockIdx.x * 256 + threadIdx.x;
    if (i >= n8) return;
    const float* p = in + (size_t)i * 8;
    u32 hw[4], lw[4];
#pragma unroll
    for (int j = 0; j < 4; ++j) {
        float a = p[2 * j], b = p[2 * j + 1];
        split2(a, b, hw[j], lw[j]);
    }
    *(uint4*)&hi[(size_t)i * 8] = make_uint4(hw[0], hw[1], hw[2], hw[3]);
    *(uint4*)&lo[(size_t)i * 8] = make_uint4(lw[0], lw[1], lw[2], lw[3]);
}

// ---------------- pre-pass: transpose + split  W[Kd][Nd] f32 -> T{h,l}[Nd][Kd] bf16 ----
__global__ __launch_bounds__(256) void transconv_kernel(
    const float* __restrict__ W, u16* __restrict__ Th, u16* __restrict__ Tl,
    int Kd, int Nd)
{
    __shared__ float t[32][36];
    const int r0 = blockIdx.y * 32;   // W row (k)
    const int c0 = blockIdx.x * 32;   // W col (n)
    const int tid = threadIdx.x;
    {
        int r = tid >> 3, c4 = (tid & 7) * 4;
        float4 v = *(const float4*)&W[(size_t)(r0 + r) * Nd + c0 + c4];
        t[r][c4 + 0] = v.x; t[r][c4 + 1] = v.y; t[r][c4 + 2] = v.z; t[r][c4 + 3] = v.w;
    }
    __syncthreads();
    int oc = tid >> 3;        // original col -> output row
    int oi = tid & 7;         // covers original rows 4*oi..4*oi+3
    u32 hw[2], lw[2];
    split2(t[4 * oi + 0][oc], t[4 * oi + 1][oc], hw[0], lw[0]);
    split2(t[4 * oi + 2][oc], t[4 * oi + 3][oc], hw[1], lw[1]);
    size_t o = (size_t)(c0 + oc) * Kd + r0 + 4 * oi;
    *(uint2*)&Th[o] = make_uint2(hw[0], hw[1]);
    *(uint2*)&Tl[o] = make_uint2(lw[0], lw[1]);
}

// ---------------- K1/K5: lora down-projection  out[M,4] = X[M,K] @ A[K,4] ----------------
__global__ __launch_bounds__(64) void lora_down_kernel(
    const float* __restrict__ X, const float* __restrict__ A,
    float* __restrict__ out, int K)
{
    const int row = blockIdx.x;
    const int lane = threadIdx.x;
    const float* xr = X + (size_t)row * K;
    float a0 = 0.f, a1 = 0.f, a2 = 0.f, a3 = 0.f;
    for (int c = lane; c < K; c += 64) {
        float xv = xr[c];
        float4 av = *(const float4*)&A[c * 4];
        a0 = fmaf(xv, av.x, a0);
        a1 = fmaf(xv, av.y, a1);
        a2 = fmaf(xv, av.z, a2);
        a3 = fmaf(xv, av.w, a3);
    }
#pragma unroll
    for (int off = 32; off > 0; off >>= 1) {
        a0 += __shfl_down(a0, off);
        a1 += __shfl_down(a1, off);
        a2 += __shfl_down(a2, off);
        a3 += __shfl_down(a3, off);
    }
    if (lane == 0) {
        float4 r; r.x = a0; r.y = a1; r.z = a2; r.w = a3;
        *(float4*)&out[(size_t)row * 4] = r;
    }
}

// ---------------- split-bf16 MFMA GEMM: C[M,N] = (Ah+Al)[M,K] @ (Bh+Bl)^T[N,K] ----------
// 128x128 tile, BK=32, 4 waves (2x2 quadrants of 64x64). bf16x3: hh + hl + lh.
// Staging: wave w DMA-stages array w via global_load_lds (16B), chunk-XOR swizzle
// c ^= (row>>1)&3 applied on the GLOBAL source (rule #21); reads apply same XOR.
template<bool OUTBF, bool LORA, bool BIAS>
__global__ __launch_bounds__(256, 2) void gemm_split_kernel(
    const u16* __restrict__ Ah, const u16* __restrict__ Al,
    const u16* __restrict__ Bh, const u16* __restrict__ Bl,
    void* __restrict__ Cout, int M, int N, int K,
    const float* __restrict__ XA, const float* __restrict__ LB,
    const float* __restrict__ bias)
{
    __shared__ __align__(16) u16 As[2][128 * 32];
    __shared__ __align__(16) u16 Bs[2][128 * 32];
    const int tid = threadIdx.x;
    const int w = tid >> 6, lane = tid & 63;
    const int lc = lane & 15, lg = lane >> 4;
    const int wr = w >> 1, wc = w & 1;
    const int m0 = blockIdx.y * 128;
    const int n0 = blockIdx.x * 128;

    // staging role: wave w owns one 8KB array (8 chunks of 1KB = 16 rows each)
    const u16* sbase = (w == 0) ? Ah : (w == 1) ? Al : (w == 2) ? Bh : Bl;
    u16* lbase = (w == 0) ? As[0] : (w == 1) ? As[1] : (w == 2) ? Bs[0] : Bs[1];
    const int rbase = (w < 2) ? m0 : n0;
    const int srow = lane >> 2;                              // row within 16-row chunk
    const int schunk = ((lane & 3) ^ ((lane >> 3) & 3)) * 8; // inverse-swizzled src k-chunk
    const u16* sptr = sbase + (size_t)(rbase + srow) * K + schunk;

    f32x4 acc[4][4];
#pragma unroll
    for (int i = 0; i < 4; ++i)
#pragma unroll
        for (int j = 0; j < 4; ++j) acc[i][j] = (f32x4){0.f, 0.f, 0.f, 0.f};

    const int aswz = (lg ^ ((lc >> 1) & 3)) * 8;
    const int aoff = (wr * 64 + lc) * 32 + aswz;
    const int boff = (wc * 64 + lc) * 32 + aswz;

    for (int k0 = 0; k0 < K; k0 += 32) {
        __syncthreads();                       // previous tile consumed
#pragma unroll
        for (int j = 0; j < 8; ++j)
            g2lds16(sptr + (size_t)(16 * j) * K + k0, lbase + j * 512);
        __syncthreads();                       // drains vmcnt -> LDS ready

        bf16x8 af[4][2], bfr[4][2];
#pragma unroll
        for (int f = 0; f < 4; ++f) {
            af[f][0]  = *(const bf16x8*)&As[0][aoff + f * 512];
            af[f][1]  = *(const bf16x8*)&As[1][aoff + f * 512];
            bfr[f][0] = *(const bf16x8*)&Bs[0][boff + f * 512];
            bfr[f][1] = *(const bf16x8*)&Bs[1][boff + f * 512];
        }
#pragma unroll
        for (int i = 0; i < 4; ++i)
#pragma unroll
            for (int j = 0; j < 4; ++j) {
                acc[i][j] = __builtin_amdgcn_mfma_f32_16x16x32_bf16(af[i][0], bfr[j][0], acc[i][j], 0, 0, 0);
                acc[i][j] = __builtin_amdgcn_mfma_f32_16x16x32_bf16(af[i][0], bfr[j][1], acc[i][j], 0, 0, 0);
                acc[i][j] = __builtin_amdgcn_mfma_f32_16x16x32_bf16(af[i][1], bfr[j][0], acc[i][j], 0, 0, 0);
            }
    }

    // epilogue: C rows = wr*64+i*16+lg*4+r, cols = wc*64+j*16+lc
#pragma unroll
    for (int j = 0; j < 4; ++j) {
        const int col = n0 + wc * 64 + j * 16 + lc;
        float lb0 = 0.f, lb1 = 0.f, lb2 = 0.f, lb3 = 0.f, bv = 0.f;
        if (LORA) {
            lb0 = LB[0 * N + col]; lb1 = LB[1 * N + col];
            lb2 = LB[2 * N + col]; lb3 = LB[3 * N + col];
        }
        if (BIAS) bv = bias[col];
#pragma unroll
        for (int i = 0; i < 4; ++i) {
#pragma unroll
            for (int r = 0; r < 4; ++r) {
                const int row = m0 + wr * 64 + i * 16 + lg * 4 + r;
                float v = acc[i][j][r];
                if (LORA) {
                    const float4 xa4 = *(const float4*)&XA[(size_t)row * 4];
                    v += LORA_SCALE * (xa4.x * lb0 + xa4.y * lb1 + xa4.z * lb2 + xa4.w * lb3);
                }
                if (BIAS) v += bv;
                if (OUTBF) ((u16*)Cout)[(size_t)row * N + col] = f2bf(v);
                else       ((float*)Cout)[(size_t)row * N + col] = v;
            }
        }
    }
}

// ---------------- K3: MFMA bf16 flash attention (bf16 qkv in, split bf16 ao out) --------
// qkv rows: [B*N][2304] bf16, Q at h*64, K at 768+h*64, V at 1536+h*64.
__global__ __launch_bounds__(256, 3) void flash_mfma_kernel(
    const u16* __restrict__ qkv, u16* __restrict__ aoh, u16* __restrict__ aol)
{
    __shared__ __align__(16) short Kl[32][72];   // [k][d] bf16, 144B rows -> 2-way-free b128
    __shared__ __align__(16) short Vl[64][40];   // V^T [d][k] bf16, 80B rows -> 2-way-free
    const int fid = blockIdx.x;
    const int bh = fid % 96;
    const int qx = fid / 96;
    const int b = bh / 12, h = bh - b * 12;
    const int tid = threadIdx.x;
    const int w = tid >> 6, lane = tid & 63;
    const int lc = lane & 15, lg = lane >> 4;
    const u16* base = qkv + (size_t)b * 1024 * 2304;
    const int q0 = qx * 128 + w * 32;

    // Q B-frags: direct bf16 16B loads (col q = lc, rows d = dc*32 + lg*8 + j)
    Frag qf[2][2];
#pragma unroll
    for (int qi = 0; qi < 2; ++qi)
#pragma unroll
        for (int dc = 0; dc < 2; ++dc)
            qf[qi][dc].v = *(const bf16x8*)&base[(size_t)(q0 + qi * 16 + lc) * 2304 + h * 64 + dc * 32 + lg * 8];

    f32x4 o[2][4];
#pragma unroll
    for (int qi = 0; qi < 2; ++qi)
#pragma unroll
        for (int df = 0; df < 4; ++df) o[qi][df] = (f32x4){0.f, 0.f, 0.f, 0.f};
    float mrow[2] = {-1e30f, -1e30f};
    float lrow[2] = {0.f, 0.f};
    const float SC = 0.125f * 1.44269504f;   // d^-0.5 * log2(e), applied to raw scores

    for (int kv0 = 0; kv0 < 1024; kv0 += 32) {
        __syncthreads();
#pragma unroll
        for (int rep = 0; rep < 2; ++rep) {
            int i = tid + rep * 256;
            int kk = i >> 4, d0 = (i & 15) * 4;
            const u16* gp = base + (size_t)(kv0 + kk) * 2304 + 768 + h * 64 + d0;
            uint2 kw = *(const uint2*)gp;
            uint2 vw = *(const uint2*)(gp + 768);
            *(uint2*)&Kl[kk][d0] = kw;
            Vl[d0 + 0][kk] = (short)(vw.x & 0xFFFF);
            Vl[d0 + 1][kk] = (short)(vw.x >> 16);
            Vl[d0 + 2][kk] = (short)(vw.y & 0xFFFF);
            Vl[d0 + 3][kk] = (short)(vw.y >> 16);
        }
        __syncthreads();

        bf16x8 kA[2][2], vA[4];
#pragma unroll
        for (int kf = 0; kf < 2; ++kf)
#pragma unroll
            for (int dc = 0; dc < 2; ++dc)
                kA[kf][dc] = *(const bf16x8*)&Kl[kf * 16 + lc][dc * 32 + lg * 8];
#pragma unroll
        for (int df = 0; df < 4; ++df)
            vA[df] = *(const bf16x8*)&Vl[df * 16 + lc][lg * 8];

#pragma unroll
        for (int qi = 0; qi < 2; ++qi) {
            f32x4 s0 = {0.f, 0.f, 0.f, 0.f}, s1 = {0.f, 0.f, 0.f, 0.f};
            s0 = __builtin_amdgcn_mfma_f32_16x16x32_bf16(kA[0][0], qf[qi][0].v, s0, 0, 0, 0);
            s0 = __builtin_amdgcn_mfma_f32_16x16x32_bf16(kA[0][1], qf[qi][1].v, s0, 0, 0, 0);
            s1 = __builtin_amdgcn_mfma_f32_16x16x32_bf16(kA[1][0], qf[qi][0].v, s1, 0, 0, 0);
            s1 = __builtin_amdgcn_mfma_f32_16x16x32_bf16(kA[1][1], qf[qi][1].v, s1, 0, 0, 0);

            float t0[4], t1[4];
#pragma unroll
            for (int r = 0; r < 4; ++r) { t0[r] = s0[r] * SC; t1[r] = s1[r] * SC; }
            float pm = fmaxf(fmaxf(fmaxf(t0[0], t0[1]), fmaxf(t0[2], t0[3])),
                             fmaxf(fmaxf(t1[0], t1[1]), fmaxf(t1[2], t1[3])));
            pm = fmaxf(pm, __shfl_xor(pm, 16, 64));
            pm = fmaxf(pm, __shfl_xor(pm, 32, 64));
            float nm = fmaxf(mrow[qi], pm);
            float corr = exp2f(mrow[qi] - nm);
            mrow[qi] = nm;
            float p0[4], p1[4];
            float rs = 0.f;
#pragma unroll
            for (int r = 0; r < 4; ++r) {
                p0[r] = exp2f(t0[r] - nm); rs += p0[r];
                p1[r] = exp2f(t1[r] - nm); rs += p1[r];
            }
            rs += __shfl_xor(rs, 16, 64);
            rs += __shfl_xor(rs, 32, 64);
            lrow[qi] = lrow[qi] * corr + rs;
#pragma unroll
            for (int df = 0; df < 4; ++df) o[qi][df] *= corr;

            // P^T -> PV B-frag via 8-shfl register exchange
            u32 w00 = (u32)f2bf(p0[0]) | ((u32)f2bf(p0[1]) << 16);
            u32 w01 = (u32)f2bf(p0[2]) | ((u32)f2bf(p0[3]) << 16);
            u32 w10 = (u32)f2bf(p1[0]) | ((u32)f2bf(p1[1]) << 16);
            u32 w11 = (u32)f2bf(p1[2]) | ((u32)f2bf(p1[3]) << 16);
            Frag pa;
            const int gsel = (lg & 1) * 2;
#pragma unroll
            for (int c = 0; c < 4; ++c) {
                int src = lc | ((gsel + (c >> 1)) << 4);
                u32 a0 = (u32)__shfl((int)((c & 1) ? w01 : w00), src, 64);
                u32 a1 = (u32)__shfl((int)((c & 1) ? w11 : w10), src, 64);
                pa.u[c] = (lg >> 1) ? a1 : a0;
            }
#pragma unroll
            for (int df = 0; df < 4; ++df)
                o[qi][df] = __builtin_amdgcn_mfma_f32_16x16x32_bf16(vA[df], pa.v, o[qi][df], 0, 0, 0);
        }
    }

    // epilogue: normalize, split to hi/lo bf16, store
#pragma unroll
    for (int qi = 0; qi < 2; ++qi) {
        float inv = 1.f / lrow[qi];
        size_t rowoff = (size_t)(b * 1024 + q0 + qi * 16 + lc) * 768 + h * 64;
#pragma unroll
        for (int df = 0; df < 4; ++df) {
            float v0 = o[qi][df][0] * inv, v1 = o[qi][df][1] * inv;
            float v2 = o[qi][df][2] * inv, v3 = o[qi][df][3] * inv;
            u32 h0, l0, h1, l1;
            split2(v0, v1, h0, l0);
            split2(v2, v3, h1, l1);
            *(uint2*)&aoh[rowoff + df * 16 + lg * 4] = make_uint2(h0, h1);
            *(uint2*)&aol[rowoff + df * 16 + lg * 4] = make_uint2(l0, l1);
        }
    }
}

// ---------------- K6: out += LORA_SCALE * pa[M,4] @ Bp[4,768] (in place) ----------------
__global__ __launch_bounds__(256) void lora_up_add_kernel(
    float* __restrict__ out, const float* __restrict__ pa,
    const float* __restrict__ Bp)
{
    const int idx = blockIdx.x * 256 + threadIdx.x;
    const int row = idx / 192;
    const int col = (idx - row * 192) * 4;
    float4 p4 = *(const float4*)&pa[(size_t)row * 4];
    float4 b0 = *(const float4*)&Bp[0 * 768 + col];
    float4 b1 = *(const float4*)&Bp[1 * 768 + col];
    float4 b2 = *(const float4*)&Bp[2 * 768 + col];
    float4 b3 = *(const float4*)&Bp[3 * 768 + col];
    float* op = &out[(size_t)row * 768 + col];
    float4 o = *(float4*)op;
    o.x += LORA_SCALE * (p4.x * b0.x + p4.y * b1.x + p4.z * b2.x + p4.w * b3.x);
    o.y += LORA_SCALE * (p4.x * b0.y + p4.y * b1.y + p4.z * b2.y + p4.w * b3.y);
    o.z += LORA_SCALE * (p4.x * b0.z + p4.y * b1.z + p4.z * b2.z + p4.w * b3.z);
    o.w += LORA_SCALE * (p4.x * b0.w + p4.y * b1.w + p4.z * b2.w + p4.w * b3.w);
    *(float4*)op = o;
}

extern "C" void kernel_launch(void* const* d_in, const int* in_sizes, int n_in,
                              void* d_out, int out_size, void* d_ws, size_t ws_size,
                              hipStream_t stream)
{
    const float* x      = (const float*)d_in[0];
    const float* W_qkv  = (const float*)d_in[1];
    const float* W_proj = (const float*)d_in[2];
    const float* b_proj = (const float*)d_in[3];
    const float* A_qkv  = (const float*)d_in[4];
    const float* B_qkv  = (const float*)d_in[5];
    const float* A_proj = (const float*)d_in[6];
    const float* B_proj = (const float*)d_in[7];
    float* out = (float*)d_out;

    char* ws = (char*)d_ws;
    float* xa    = (float*)(ws);                      // 131072 B
    float* pa    = (float*)(ws + 131072);             // 131072 B
    u16* xhi     = (u16*)(ws + 262144);               // 12582912 B
    u16* xlo     = (u16*)(ws + 12845056);             // 12582912 B
    u16* wqh     = (u16*)(ws + 25427968);             // 3538944 B  (W_qkv^T hi [2304][768])
    u16* wql     = (u16*)(ws + 28966912);             // 3538944 B
    u16* wph     = (u16*)(ws + 32505856);             // 1179648 B  (W_proj^T hi [768][768])
    u16* wpl     = (u16*)(ws + 33685504);             // 1179648 B
    u16* qkv     = (u16*)(ws + 34865152);             // 37748736 B (bf16 [8192][2304])
    u16* aoh     = (u16*)(ws + 72613888);             // 12582912 B
    u16* aol     = (u16*)(ws + 85196800);             // 12582912 B  (end 97779712)

    const int M = 8192;   // B*N

    // pre-pass: split x; transpose+split weights
    split_kernel<<<dim3(3072), dim3(256), 0, stream>>>(x, xhi, xlo, M * 768 / 8);
    transconv_kernel<<<dim3(72, 24), dim3(256), 0, stream>>>(W_qkv, wqh, wql, 768, 2304);
    transconv_kernel<<<dim3(24, 24), dim3(256), 0, stream>>>(W_proj, wph, wpl, 768, 768);
    // 1) xa = x @ A_qkv
    lora_down_kernel<<<dim3(M), dim3(64), 0, stream>>>(x, A_qkv, xa, 768);
    // 2) qkv(bf16) = x @ W_qkv + 8 * xa @ B_qkv   (split-bf16 MFMA)
    gemm_split_kernel<true, true, false><<<dim3(18, 64), dim3(256), 0, stream>>>(
        xhi, xlo, wqh, wql, qkv, M, 2304, 768, xa, B_qkv, nullptr);
    // 3) MFMA flash attention -> ao hi/lo
    flash_mfma_kernel<<<dim3(768), dim3(256), 0, stream>>>(qkv, aoh, aol);
    // 4) out = ao @ W_proj + b_proj   (split-bf16 MFMA, fp32 out)
    gemm_split_kernel<false, false, true><<<dim3(6, 64), dim3(256), 0, stream>>>(
        aoh, aol, wph, wpl, out, M, 768, 768, nullptr, nullptr, b_proj);
    // 5) pa = out @ A_proj
    lora_down_kernel<<<dim3(M), dim3(64), 0, stream>>>(out, A_proj, pa, 768);
    // 6) out += 8 * pa @ B_proj
    lora_up_add_kernel<<<dim3(6144), dim3(256), 0, stream>>>(out, pa, B_proj);
}

// Round 5
// 265.872 us; speedup vs baseline: 4.5451x; 1.2846x over previous
//
#include <hip/hip_runtime.h>
#include <hip/hip_bf16.h>
#include <math.h>

#define LORA_SCALE 8.0f

typedef __attribute__((ext_vector_type(8))) short bf16x8;
typedef __attribute__((ext_vector_type(4))) float f32x4;
typedef unsigned short u16;
typedef unsigned int u32;

__device__ __forceinline__ u16 f2bf(float f) {
    u32 u = __float_as_uint(f);
    u += 0x7FFFu + ((u >> 16) & 1u);      // RNE to bf16
    return (u16)(u >> 16);
}
__device__ __forceinline__ float bf2f(u16 s) {
    return __uint_as_float(((u32)s) << 16);
}
__device__ __forceinline__ u32 pack2(float lo, float hi) {
    return (u32)f2bf(lo) | ((u32)f2bf(hi) << 16);
}
__device__ __forceinline__ void split2(float a, float b, u32& hw, u32& lw) {
    u16 ha = f2bf(a), hb = f2bf(b);
    float ra = a - bf2f(ha), rb = b - bf2f(hb);
    hw = (u32)ha | ((u32)hb << 16);
    lw = (u32)f2bf(ra) | ((u32)f2bf(rb) << 16);
}
__device__ __forceinline__ void g2lds16(const void* g, void* l) {
    __builtin_amdgcn_global_load_lds(
        (const __attribute__((address_space(1))) void*)g,
        (__attribute__((address_space(3))) void*)l, 16, 0, 0);
}

union Frag { bf16x8 v; u32 u[4]; };

// ---------------- pre-pass: split f32 -> bf16 hi/lo (8 elems/thread) ----------------
__global__ __launch_bounds__(256) void split_kernel(
    const float* __restrict__ in, u16* __restrict__ hi, u16* __restrict__ lo, int n8)
{
    int i = blockIdx.x * 256 + threadIdx.x;
    if (i >= n8) return;
    const float* p = in + (size_t)i * 8;
    u32 hw[4], lw[4];
#pragma unroll
    for (int j = 0; j < 4; ++j) split2(p[2 * j], p[2 * j + 1], hw[j], lw[j]);
    *(uint4*)&hi[(size_t)i * 8] = make_uint4(hw[0], hw[1], hw[2], hw[3]);
    *(uint4*)&lo[(size_t)i * 8] = make_uint4(lw[0], lw[1], lw[2], lw[3]);
}

// ---------------- pre-pass: transpose + split  W[Kd][Nd] f32 -> T{h,l}[Nd][Kd] bf16 ----
__global__ __launch_bounds__(256) void transconv_kernel(
    const float* __restrict__ W, u16* __restrict__ Th, u16* __restrict__ Tl,
    int Kd, int Nd)
{
    __shared__ float t[32][36];
    const int r0 = blockIdx.y * 32;
    const int c0 = blockIdx.x * 32;
    const int tid = threadIdx.x;
    {
        int r = tid >> 3, c4 = (tid & 7) * 4;
        float4 v = *(const float4*)&W[(size_t)(r0 + r) * Nd + c0 + c4];
        t[r][c4 + 0] = v.x; t[r][c4 + 1] = v.y; t[r][c4 + 2] = v.z; t[r][c4 + 3] = v.w;
    }
    __syncthreads();
    int oc = tid >> 3;
    int oi = tid & 7;
    u32 hw[2], lw[2];
    split2(t[4 * oi + 0][oc], t[4 * oi + 1][oc], hw[0], lw[0]);
    split2(t[4 * oi + 2][oc], t[4 * oi + 3][oc], hw[1], lw[1]);
    size_t o = (size_t)(c0 + oc) * Kd + r0 + 4 * oi;
    *(uint2*)&Th[o] = make_uint2(hw[0], hw[1]);
    *(uint2*)&Tl[o] = make_uint2(lw[0], lw[1]);
}

// ---------------- K1: lora down-projection  xa[M,4] = X[M,K] @ A[K,4] ----------------
__global__ __launch_bounds__(64) void lora_down_kernel(
    const float* __restrict__ X, const float* __restrict__ A,
    float* __restrict__ out, int K)
{
    const int row = blockIdx.x;
    const int lane = threadIdx.x;
    const float* xr = X + (size_t)row * K;
    float a0 = 0.f, a1 = 0.f, a2 = 0.f, a3 = 0.f;
    for (int c = lane; c < K; c += 64) {
        float xv = xr[c];
        float4 av = *(const float4*)&A[c * 4];
        a0 = fmaf(xv, av.x, a0);
        a1 = fmaf(xv, av.y, a1);
        a2 = fmaf(xv, av.z, a2);
        a3 = fmaf(xv, av.w, a3);
    }
#pragma unroll
    for (int off = 32; off > 0; off >>= 1) {
        a0 += __shfl_down(a0, off);
        a1 += __shfl_down(a1, off);
        a2 += __shfl_down(a2, off);
        a3 += __shfl_down(a3, off);
    }
    if (lane == 0) {
        float4 r; r.x = a0; r.y = a1; r.z = a2; r.w = a3;
        *(float4*)&out[(size_t)row * 4] = r;
    }
}

// ---------------- split-bf16 MFMA GEMM, 2-phase double-buffered pipeline --------------
// C[M,N] = (Ah+Al)[M,K] @ (Bh+Bl)^T[N,K]; 128x128 tile, BK=32, 4 waves (2x2 quadrants).
// bf16x3 via SWAPPED mfma(B,A): lane holds 4 consecutive output cols -> vector stores.
// Wave w DMA-stages its array (global_load_lds, 16B), chunk-XOR swizzle on the GLOBAL
// source. One barrier per K-step: prefetch t+1 into buf^1 before computing t (T3-min).
// Grid 1-D, XCD-chunked decode (T1): lid = (bid%8)*(nwg/8)+bid/8.
template<bool OUTBF, bool LORA, bool BIAS>
__global__ __launch_bounds__(256, 2) void gemm_split_kernel(
    const u16* __restrict__ Ah, const u16* __restrict__ Al,
    const u16* __restrict__ Bh, const u16* __restrict__ Bl,
    void* __restrict__ Cout, int M, int N, int K,
    const float* __restrict__ XA, const float* __restrict__ LB,
    const float* __restrict__ bias)
{
    __shared__ __align__(16) u16 Ls[2][4][4096];   // [dbuf][Ahi,Alo,Bhi,Blo][128*32]
    const int tid = threadIdx.x;
    const int w = tid >> 6, lane = tid & 63;
    const int lc = lane & 15, lg = lane >> 4;
    const int wr = w >> 1, wc = w & 1;

    const unsigned nbx = (unsigned)N >> 7;
    const unsigned cpx = gridDim.x >> 3;
    const unsigned bid = blockIdx.x;
    const unsigned lid = (bid & 7) * cpx + (bid >> 3);
    const int m0 = (int)(lid / nbx) * 128;
    const int n0 = (int)(lid % nbx) * 128;

    const u16* sbase = (w == 0) ? Ah : (w == 1) ? Al : (w == 2) ? Bh : Bl;
    const int rbase = (w < 2) ? m0 : n0;
    const int srow = lane >> 2;
    const int schunk = ((lane & 3) ^ ((lane >> 3) & 3)) * 8;
    const u16* sptr = sbase + (size_t)(rbase + srow) * K + schunk;

    f32x4 acc[4][4];
#pragma unroll
    for (int i = 0; i < 4; ++i)
#pragma unroll
        for (int j = 0; j < 4; ++j) acc[i][j] = (f32x4){0.f, 0.f, 0.f, 0.f};

    const int aswz = (lg ^ ((lc >> 1) & 3)) * 8;
    const int aoff = (wr * 64 + lc) * 32 + aswz;
    const int boff = (wc * 64 + lc) * 32 + aswz;

    // prologue: stage k0=0 into buffer 0
#pragma unroll
    for (int j = 0; j < 8; ++j)
        g2lds16(sptr + (size_t)(16 * j) * K, &Ls[0][w][j * 512]);
    __syncthreads();

    for (int kp = 0; kp < K; kp += 64) {
#pragma unroll
        for (int half = 0; half < 2; ++half) {
            const int k0 = kp + half * 32;
            if (k0 + 32 < K) {
#pragma unroll
                for (int j = 0; j < 8; ++j)
                    g2lds16(sptr + (size_t)(16 * j) * K + (k0 + 32), &Ls[half ^ 1][w][j * 512]);
            }
            const u16* cb = &Ls[half][0][0];
            bf16x8 af[4][2], bfr[4][2];
#pragma unroll
            for (int f = 0; f < 4; ++f) {
                af[f][0]  = *(const bf16x8*)&cb[0     + aoff + f * 512];
                af[f][1]  = *(const bf16x8*)&cb[4096  + aoff + f * 512];
                bfr[f][0] = *(const bf16x8*)&cb[8192  + boff + f * 512];
                bfr[f][1] = *(const bf16x8*)&cb[12288 + boff + f * 512];
            }
#pragma unroll
            for (int i = 0; i < 4; ++i)
#pragma unroll
                for (int j = 0; j < 4; ++j) {
                    acc[i][j] = __builtin_amdgcn_mfma_f32_16x16x32_bf16(bfr[j][0], af[i][0], acc[i][j], 0, 0, 0);
                    acc[i][j] = __builtin_amdgcn_mfma_f32_16x16x32_bf16(bfr[j][0], af[i][1], acc[i][j], 0, 0, 0);
                    acc[i][j] = __builtin_amdgcn_mfma_f32_16x16x32_bf16(bfr[j][1], af[i][0], acc[i][j], 0, 0, 0);
                }
            __syncthreads();   // one barrier per K-step; prefetch drains here
        }
    }

    // epilogue: lane holds rows m0+wr*64+i*16+lc, cols n0+wc*64+j*16+lg*4..+3
    float4 xa4[4];
    if (LORA) {
#pragma unroll
        for (int i = 0; i < 4; ++i)
            xa4[i] = *(const float4*)&XA[(size_t)(m0 + wr * 64 + i * 16 + lc) * 4];
    }
#pragma unroll
    for (int j = 0; j < 4; ++j) {
        const int col = n0 + wc * 64 + j * 16 + lg * 4;
        float4 lb0, lb1, lb2, lb3, bb;
        if (LORA) {
            lb0 = *(const float4*)&LB[0 * N + col];
            lb1 = *(const float4*)&LB[1 * N + col];
            lb2 = *(const float4*)&LB[2 * N + col];
            lb3 = *(const float4*)&LB[3 * N + col];
        }
        if (BIAS) bb = *(const float4*)&bias[col];
#pragma unroll
        for (int i = 0; i < 4; ++i) {
            const int row = m0 + wr * 64 + i * 16 + lc;
            float v0 = acc[i][j][0], v1 = acc[i][j][1], v2 = acc[i][j][2], v3 = acc[i][j][3];
            if (LORA) {
                v0 += LORA_SCALE * (xa4[i].x * lb0.x + xa4[i].y * lb1.x + xa4[i].z * lb2.x + xa4[i].w * lb3.x);
                v1 += LORA_SCALE * (xa4[i].x * lb0.y + xa4[i].y * lb1.y + xa4[i].z * lb2.y + xa4[i].w * lb3.y);
                v2 += LORA_SCALE * (xa4[i].x * lb0.z + xa4[i].y * lb1.z + xa4[i].z * lb2.z + xa4[i].w * lb3.z);
                v3 += LORA_SCALE * (xa4[i].x * lb0.w + xa4[i].y * lb1.w + xa4[i].z * lb2.w + xa4[i].w * lb3.w);
            }
            if (BIAS) { v0 += bb.x; v1 += bb.y; v2 += bb.z; v3 += bb.w; }
            if (OUTBF) {
                uint2 o2; o2.x = pack2(v0, v1); o2.y = pack2(v2, v3);
                *(uint2*)&((u16*)Cout)[(size_t)row * N + col] = o2;
            } else {
                *(float4*)&((float*)Cout)[(size_t)row * N + col] = make_float4(v0, v1, v2, v3);
            }
        }
    }
}

// ---------------- K3: MFMA bf16 flash attention (T14 issue-early/write-late) ----------
__global__ __launch_bounds__(256, 3) void flash_mfma_kernel(
    const u16* __restrict__ qkv, u16* __restrict__ aoh, u16* __restrict__ aol)
{
    __shared__ __align__(16) short Kl[32][72];
    __shared__ __align__(16) short Vl[64][40];
    const int fid = blockIdx.x;
    const int bh = fid % 96;
    const int qx = fid / 96;
    const int b = bh / 12, h = bh - b * 12;
    const int tid = threadIdx.x;
    const int w = tid >> 6, lane = tid & 63;
    const int lc = lane & 15, lg = lane >> 4;
    const u16* base = qkv + (size_t)b * 1024 * 2304;
    const int q0 = qx * 128 + w * 32;

    Frag qf[2][2];
#pragma unroll
    for (int qi = 0; qi < 2; ++qi)
#pragma unroll
        for (int dc = 0; dc < 2; ++dc)
            qf[qi][dc].v = *(const bf16x8*)&base[(size_t)(q0 + qi * 16 + lc) * 2304 + h * 64 + dc * 32 + lg * 8];

    f32x4 o[2][4];
#pragma unroll
    for (int qi = 0; qi < 2; ++qi)
#pragma unroll
        for (int df = 0; df < 4; ++df) o[qi][df] = (f32x4){0.f, 0.f, 0.f, 0.f};
    float mrow[2] = {-1e30f, -1e30f};
    float lrow[2] = {0.f, 0.f};
    const float SC = 0.125f * 1.44269504f;

    const u16* kvbase = base + 768 + h * 64;
    const int skk = tid >> 4, sd0 = (tid & 15) * 4;
    uint2 pk[2], pv[2];
#pragma unroll
    for (int rep = 0; rep < 2; ++rep) {
        const u16* gp = kvbase + (size_t)(skk + rep * 16) * 2304 + sd0;
        pk[rep] = *(const uint2*)gp;
        pv[rep] = *(const uint2*)(gp + 768);
    }

    for (int kv0 = 0; kv0 < 1024; kv0 += 32) {
        __syncthreads();
#pragma unroll
        for (int rep = 0; rep < 2; ++rep) {
            int kk = skk + rep * 16;
            *(uint2*)&Kl[kk][sd0] = pk[rep];
            Vl[sd0 + 0][kk] = (short)(pv[rep].x & 0xFFFF);
            Vl[sd0 + 1][kk] = (short)(pv[rep].x >> 16);
            Vl[sd0 + 2][kk] = (short)(pv[rep].y & 0xFFFF);
            Vl[sd0 + 3][kk] = (short)(pv[rep].y >> 16);
        }
        if (kv0 + 32 < 1024) {
#pragma unroll
            for (int rep = 0; rep < 2; ++rep) {
                const u16* gp = kvbase + (size_t)(kv0 + 32 + skk + rep * 16) * 2304 + sd0;
                pk[rep] = *(const uint2*)gp;
                pv[rep] = *(const uint2*)(gp + 768);
            }
        }
        __syncthreads();

        bf16x8 kA[2][2], vA[4];
#pragma unroll
        for (int kf = 0; kf < 2; ++kf)
#pragma unroll
            for (int dc = 0; dc < 2; ++dc)
                kA[kf][dc] = *(const bf16x8*)&Kl[kf * 16 + lc][dc * 32 + lg * 8];
#pragma unroll
        for (int df = 0; df < 4; ++df)
            vA[df] = *(const bf16x8*)&Vl[df * 16 + lc][lg * 8];

#pragma unroll
        for (int qi = 0; qi < 2; ++qi) {
            f32x4 s0 = {0.f, 0.f, 0.f, 0.f}, s1 = {0.f, 0.f, 0.f, 0.f};
            s0 = __builtin_amdgcn_mfma_f32_16x16x32_bf16(kA[0][0], qf[qi][0].v, s0, 0, 0, 0);
            s0 = __builtin_amdgcn_mfma_f32_16x16x32_bf16(kA[0][1], qf[qi][1].v, s0, 0, 0, 0);
            s1 = __builtin_amdgcn_mfma_f32_16x16x32_bf16(kA[1][0], qf[qi][0].v, s1, 0, 0, 0);
            s1 = __builtin_amdgcn_mfma_f32_16x16x32_bf16(kA[1][1], qf[qi][1].v, s1, 0, 0, 0);

            float t0[4], t1[4];
#pragma unroll
            for (int r = 0; r < 4; ++r) { t0[r] = s0[r] * SC; t1[r] = s1[r] * SC; }
            float pm = fmaxf(fmaxf(fmaxf(t0[0], t0[1]), fmaxf(t0[2], t0[3])),
                             fmaxf(fmaxf(t1[0], t1[1]), fmaxf(t1[2], t1[3])));
            pm = fmaxf(pm, __shfl_xor(pm, 16, 64));
            pm = fmaxf(pm, __shfl_xor(pm, 32, 64));
            float nm = fmaxf(mrow[qi], pm);
            float corr = exp2f(mrow[qi] - nm);
            mrow[qi] = nm;
            float p0[4], p1[4];
            float rs = 0.f;
#pragma unroll
            for (int r = 0; r < 4; ++r) {
                p0[r] = exp2f(t0[r] - nm); rs += p0[r];
                p1[r] = exp2f(t1[r] - nm); rs += p1[r];
            }
            rs += __shfl_xor(rs, 16, 64);
            rs += __shfl_xor(rs, 32, 64);
            lrow[qi] = lrow[qi] * corr + rs;
#pragma unroll
            for (int df = 0; df < 4; ++df) o[qi][df] *= corr;

            u32 w00 = pack2(p0[0], p0[1]);
            u32 w01 = pack2(p0[2], p0[3]);
            u32 w10 = pack2(p1[0], p1[1]);
            u32 w11 = pack2(p1[2], p1[3]);
            Frag pa;
            const int gsel = (lg & 1) * 2;
#pragma unroll
            for (int c = 0; c < 4; ++c) {
                int src = lc | ((gsel + (c >> 1)) << 4);
                u32 a0 = (u32)__shfl((int)((c & 1) ? w01 : w00), src, 64);
                u32 a1 = (u32)__shfl((int)((c & 1) ? w11 : w10), src, 64);
                pa.u[c] = (lg >> 1) ? a1 : a0;
            }
#pragma unroll
            for (int df = 0; df < 4; ++df)
                o[qi][df] = __builtin_amdgcn_mfma_f32_16x16x32_bf16(vA[df], pa.v, o[qi][df], 0, 0, 0);
        }
    }

#pragma unroll
    for (int qi = 0; qi < 2; ++qi) {
        float inv = 1.f / lrow[qi];
        size_t rowoff = (size_t)(b * 1024 + q0 + qi * 16 + lc) * 768 + h * 64;
#pragma unroll
        for (int df = 0; df < 4; ++df) {
            float v0 = o[qi][df][0] * inv, v1 = o[qi][df][1] * inv;
            float v2 = o[qi][df][2] * inv, v3 = o[qi][df][3] * inv;
            u32 h0, l0, h1, l1;
            split2(v0, v1, h0, l0);
            split2(v2, v3, h1, l1);
            *(uint2*)&aoh[rowoff + df * 16 + lg * 4] = make_uint2(h0, h1);
            *(uint2*)&aol[rowoff + df * 16 + lg * 4] = make_uint2(l0, l1);
        }
    }
}

// ---------------- K5+K6 fused: out += 8 * (out @ A_proj) @ B_proj, one row/block ------
__global__ __launch_bounds__(64) void lora_proj_fused_kernel(
    float* __restrict__ out, const float* __restrict__ A, const float* __restrict__ Bp)
{
    const int row = blockIdx.x;
    const int lane = threadIdx.x;
    float* orow = out + (size_t)row * 768;
    float4 v[3];
    float a0 = 0.f, a1 = 0.f, a2 = 0.f, a3 = 0.f;
#pragma unroll
    for (int s = 0; s < 3; ++s) {
        const int c = s * 256 + lane * 4;
        v[s] = *(const float4*)&orow[c];
        const float* ap = &A[(size_t)c * 4];
        float4 A0 = *(const float4*)&ap[0];
        float4 A1 = *(const float4*)&ap[4];
        float4 A2 = *(const float4*)&ap[8];
        float4 A3 = *(const float4*)&ap[12];
        a0 = fmaf(v[s].x, A0.x, a0); a1 = fmaf(v[s].x, A0.y, a1);
        a2 = fmaf(v[s].x, A0.z, a2); a3 = fmaf(v[s].x, A0.w, a3);
        a0 = fmaf(v[s].y, A1.x, a0); a1 = fmaf(v[s].y, A1.y, a1);
        a2 = fmaf(v[s].y, A1.z, a2); a3 = fmaf(v[s].y, A1.w, a3);
        a0 = fmaf(v[s].z, A2.x, a0); a1 = fmaf(v[s].z, A2.y, a1);
        a2 = fmaf(v[s].z, A2.z, a2); a3 = fmaf(v[s].z, A2.w, a3);
        a0 = fmaf(v[s].w, A3.x, a0); a1 = fmaf(v[s].w, A3.y, a1);
        a2 = fmaf(v[s].w, A3.z, a2); a3 = fmaf(v[s].w, A3.w, a3);
    }
#pragma unroll
    for (int off = 1; off < 64; off <<= 1) {
        a0 += __shfl_xor(a0, off);
        a1 += __shfl_xor(a1, off);
        a2 += __shfl_xor(a2, off);
        a3 += __shfl_xor(a3, off);
    }
    a0 *= LORA_SCALE; a1 *= LORA_SCALE; a2 *= LORA_SCALE; a3 *= LORA_SCALE;
#pragma unroll
    for (int s = 0; s < 3; ++s) {
        const int c = s * 256 + lane * 4;
        float4 b0 = *(const float4*)&Bp[0 * 768 + c];
        float4 b1 = *(const float4*)&Bp[1 * 768 + c];
        float4 b2 = *(const float4*)&Bp[2 * 768 + c];
        float4 b3 = *(const float4*)&Bp[3 * 768 + c];
        float4 r = v[s];
        r.x += a0 * b0.x + a1 * b1.x + a2 * b2.x + a3 * b3.x;
        r.y += a0 * b0.y + a1 * b1.y + a2 * b2.y + a3 * b3.y;
        r.z += a0 * b0.z + a1 * b1.z + a2 * b2.z + a3 * b3.z;
        r.w += a0 * b0.w + a1 * b1.w + a2 * b2.w + a3 * b3.w;
        *(float4*)&orow[c] = r;
    }
}

extern "C" void kernel_launch(void* const* d_in, const int* in_sizes, int n_in,
                              void* d_out, int out_size, void* d_ws, size_t ws_size,
                              hipStream_t stream)
{
    const float* x      = (const float*)d_in[0];
    const float* W_qkv  = (const float*)d_in[1];
    const float* W_proj = (const float*)d_in[2];
    const float* b_proj = (const float*)d_in[3];
    const float* A_qkv  = (const float*)d_in[4];
    const float* B_qkv  = (const float*)d_in[5];
    const float* A_proj = (const float*)d_in[6];
    const float* B_proj = (const float*)d_in[7];
    float* out = (float*)d_out;

    char* ws = (char*)d_ws;
    float* xa    = (float*)(ws);                      // 131072 B
    u16* xhi     = (u16*)(ws + 262144);               // 12582912 B
    u16* xlo     = (u16*)(ws + 12845056);             // 12582912 B
    u16* wqh     = (u16*)(ws + 25427968);             // 3538944 B
    u16* wql     = (u16*)(ws + 28966912);             // 3538944 B
    u16* wph     = (u16*)(ws + 32505856);             // 1179648 B
    u16* wpl     = (u16*)(ws + 33685504);             // 1179648 B
    u16* qkv     = (u16*)(ws + 34865152);             // 37748736 B
    u16* aoh     = (u16*)(ws + 72613888);             // 12582912 B
    u16* aol     = (u16*)(ws + 85196800);             // 12582912 B (end 97779712)

    const int M = 8192;

    split_kernel<<<dim3(3072), dim3(256), 0, stream>>>(x, xhi, xlo, M * 768 / 8);
    transconv_kernel<<<dim3(72, 24), dim3(256), 0, stream>>>(W_qkv, wqh, wql, 768, 2304);
    transconv_kernel<<<dim3(24, 24), dim3(256), 0, stream>>>(W_proj, wph, wpl, 768, 768);
    lora_down_kernel<<<dim3(M), dim3(64), 0, stream>>>(x, A_qkv, xa, 768);
    gemm_split_kernel<true, true, false><<<dim3(1152), dim3(256), 0, stream>>>(
        xhi, xlo, wqh, wql, qkv, M, 2304, 768, xa, B_qkv, nullptr);
    flash_mfma_kernel<<<dim3(768), dim3(256), 0, stream>>>(qkv, aoh, aol);
    gemm_split_kernel<false, false, true><<<dim3(384), dim3(256), 0, stream>>>(
        aoh, aol, wph, wpl, out, M, 768, 768, nullptr, nullptr, b_proj);
    lora_proj_fused_kernel<<<dim3(M), dim3(64), 0, stream>>>(out, A_proj, B_proj);
}